// Round 1
// baseline (100.558 us; speedup 1.0000x reference)
//
#include <hip/hip_runtime.h>

#define BB 32
#define CC 16
#define HH 256
#define WW 256
#define HWSZ (HH * WW)

__global__ __launch_bounds__(256) void st_bilinear_kernel(
    const float* __restrict__ input,   // [B,C,H,W]
    const float* __restrict__ theta,   // [B,6]
    float* __restrict__ out)           // [B,C,H,W]
{
    int n = blockIdx.x * blockDim.x + threadIdx.x;   // over B*H*W
    int b   = n >> 16;          // / (H*W)
    int rem = n & 0xFFFF;
    int oy  = rem >> 8;         // / W
    int ox  = rem & 0xFF;       // % W

    const float* th = theta + b * 6;
    float t0 = th[0], t1 = th[1], t2 = th[2];
    float t3 = th[3], t4 = th[4], t5 = th[5];

    const float step = 2.0f / 255.0f;
    float gx = -1.0f + ox * step;
    float gy = -1.0f + oy * step;

    float xs = t0 * gx + t1 * gy + t2;
    float ys = t3 * gx + t4 * gy + t5;
    xs = fminf(fmaxf(xs, -1.0f), 1.0f);
    ys = fminf(fmaxf(ys, -1.0f), 1.0f);

    float x = (xs + 1.0f) * 0.5f * (WW - 1);
    float y = (ys + 1.0f) * 0.5f * (HH - 1);

    float x0f = floorf(x);
    float y0f = floorf(y);
    int x0 = (int)x0f;
    int y0 = (int)y0f;
    int x1 = min(x0 + 1, WW - 1);
    int y1 = min(y0 + 1, HH - 1);

    float fx = x - x0f;
    float fy = y - y0f;
    float wa = (1.0f - fx) * (1.0f - fy);   // (y0, x0)
    float wb = (1.0f - fx) * fy;            // (y1, x0)
    float wc = fx * (1.0f - fy);            // (y0, x1)
    float wd = fx * fy;                     // (y1, x1)

    int oa = y0 * WW + x0;
    int ob = y1 * WW + x0;
    int oc = y0 * WW + x1;
    int od = y1 * WW + x1;

    const float* ibase = input + (size_t)b * CC * HWSZ;
    float* obase = out + (size_t)b * CC * HWSZ + oy * WW + ox;

    #pragma unroll
    for (int c = 0; c < CC; ++c) {
        const float* p = ibase + c * HWSZ;
        float Ia = p[oa];
        float Ib = p[ob];
        float Ic = p[oc];
        float Id = p[od];
        obase[c * HWSZ] = wa * Ia + wb * Ib + wc * Ic + wd * Id;
    }
}

extern "C" void kernel_launch(void* const* d_in, const int* in_sizes, int n_in,
                              void* d_out, int out_size, void* d_ws, size_t ws_size,
                              hipStream_t stream) {
    const float* input = (const float*)d_in[0];
    const float* theta = (const float*)d_in[1];
    float* out = (float*)d_out;

    const int total = BB * HH * WW;           // 2,097,152 threads
    dim3 block(256);
    dim3 grid(total / 256);                   // 8192 blocks
    hipLaunchKernelGGL(st_bilinear_kernel, grid, block, 0, stream,
                       input, theta, out);
}

// Round 2
// 96.671 us; speedup vs baseline: 1.0402x; 1.0402x over previous
//
#include <hip/hip_runtime.h>

#define BB 32
#define CC 16
#define HH 256
#define WW 256
#define HWSZ (HH * WW)
#define ROWS 4
#define NTILES (HH / ROWS)          // 64 tiles per image
#define NBLK (BB * NTILES)          // 2048 blocks
#define NXCD 8

__global__ __launch_bounds__(256) void st_bilinear_rows_kernel(
    const float* __restrict__ input,   // [B,C,H,W]
    const float* __restrict__ theta,   // [B,6]
    float* __restrict__ out)           // [B,C,H,W]
{
    // Chunked XCD swizzle: hardware assigns blockIdx.x round-robin across the
    // 8 XCDs; remap so each XCD processes a CONTIGUOUS chunk of tiles (4 full
    // images), keeping shared input rows in that XCD's private L2.
    int bid = blockIdx.x;
    const int chunk = NBLK / NXCD;                 // 256
    int wg = (bid & (NXCD - 1)) * chunk + (bid >> 3);

    int b   = wg / NTILES;
    int ty  = wg - b * NTILES;
    int oy0 = ty * ROWS;
    int ox  = threadIdx.x;

    const float* th = theta + b * 6;
    float t0 = th[0], t1 = th[1], t2 = th[2];
    float t3 = th[3], t4 = th[4], t5 = th[5];

    const float step = 2.0f / 255.0f;
    float gx = -1.0f + ox * step;

    int   off_a[ROWS], off_b[ROWS], off_c[ROWS], off_d[ROWS];
    float w_a[ROWS], w_b[ROWS], w_c[ROWS], w_d[ROWS];

    #pragma unroll
    for (int r = 0; r < ROWS; ++r) {
        float gy = -1.0f + (oy0 + r) * step;

        float xs = t0 * gx + t1 * gy + t2;
        float ys = t3 * gx + t4 * gy + t5;
        xs = fminf(fmaxf(xs, -1.0f), 1.0f);
        ys = fminf(fmaxf(ys, -1.0f), 1.0f);

        float x = (xs + 1.0f) * 0.5f * (WW - 1);
        float y = (ys + 1.0f) * 0.5f * (HH - 1);

        float x0f = floorf(x);
        float y0f = floorf(y);
        int x0 = (int)x0f;
        int y0 = (int)y0f;
        int x1 = min(x0 + 1, WW - 1);
        int y1 = min(y0 + 1, HH - 1);

        float fx = x - x0f;
        float fy = y - y0f;
        w_a[r] = (1.0f - fx) * (1.0f - fy);   // (y0, x0)
        w_b[r] = (1.0f - fx) * fy;            // (y1, x0)
        w_c[r] = fx * (1.0f - fy);            // (y0, x1)
        w_d[r] = fx * fy;                     // (y1, x1)

        off_a[r] = y0 * WW + x0;
        off_b[r] = y1 * WW + x0;
        off_c[r] = y0 * WW + x1;
        off_d[r] = y1 * WW + x1;
    }

    const float* ibase = input + (size_t)b * CC * HWSZ;
    float* obase = out + (size_t)b * CC * HWSZ + oy0 * WW + ox;

    #pragma unroll
    for (int c = 0; c < CC; ++c) {
        const float* p = ibase + c * HWSZ;
        float* q = obase + c * HWSZ;
        #pragma unroll
        for (int r = 0; r < ROWS; ++r) {
            float Ia = p[off_a[r]];
            float Ib = p[off_b[r]];
            float Ic = p[off_c[r]];
            float Id = p[off_d[r]];
            q[r * WW] = w_a[r] * Ia + w_b[r] * Ib + w_c[r] * Ic + w_d[r] * Id;
        }
    }
}

extern "C" void kernel_launch(void* const* d_in, const int* in_sizes, int n_in,
                              void* d_out, int out_size, void* d_ws, size_t ws_size,
                              hipStream_t stream) {
    const float* input = (const float*)d_in[0];
    const float* theta = (const float*)d_in[1];
    float* out = (float*)d_out;

    dim3 block(256);
    dim3 grid(NBLK);                 // 2048 blocks
    hipLaunchKernelGGL(st_bilinear_rows_kernel, grid, block, 0, stream,
                       input, theta, out);
}

// Round 3
// 54.839 us; speedup vs baseline: 1.8337x; 1.7628x over previous
//
#include <hip/hip_runtime.h>

#define BB 32
#define CC 16
#define HH 256
#define WW 256
#define HWSZ (HH * WW)
#define ROWS 2
#define NBLK (BB * HH / ROWS)   // 4096 blocks
#define NXCD 8

typedef float f2 __attribute__((ext_vector_type(2)));

__global__ __launch_bounds__(256) void st_bilinear_pair_kernel(
    const float* __restrict__ input,   // [B,C,H,W]
    const float* __restrict__ theta,   // [B,6]
    float* __restrict__ out)           // [B,C,H,W]
{
    // Chunked XCD swizzle: each XCD gets a contiguous range of tiles
    // (4 consecutive images) so overlapping input rows stay in its L2.
    int bid = blockIdx.x;
    int wg = (bid & (NXCD - 1)) * (NBLK / NXCD) + (bid >> 3);

    int b  = wg >> 7;                       // / (HH/ROWS = 128)
    int ty = wg & 127;
    int oy = ty * ROWS + (threadIdx.x >> 7);    // 2 rows per block
    int ox0 = (threadIdx.x & 127) * 2;          // 2 x-pixels per thread

    const float* th = theta + b * 6;
    float t0 = th[0], t1 = th[1], t2 = th[2];
    float t3 = th[3], t4 = th[4], t5 = th[5];

    const float step = 2.0f / 255.0f;
    float gy = -1.0f + oy * step;
    float cx = t1 * gy + t2;    // x = t0*gx + cx
    float cy = t4 * gy + t5;    // y = t3*gx + cy

    int   off[2];
    float w00[2], w01[2], w10[2], w11[2];

    #pragma unroll
    for (int i = 0; i < 2; ++i) {
        float gx = -1.0f + (ox0 + i) * step;
        float xs = fminf(fmaxf(t0 * gx + cx, -1.0f), 1.0f);
        float ys = fminf(fmaxf(t3 * gx + cy, -1.0f), 1.0f);
        float x = (xs + 1.0f) * 127.5f;     // [0, 255]
        float y = (ys + 1.0f) * 127.5f;

        // bx = min(floor(x), 254); fx = x - bx in [0,1].
        // fx==1 at the clamp boundary reproduces the reference's
        // index-clamp semantics exactly (selects p[255]).
        float bxf = fminf(floorf(x), 254.0f);
        float byf = fminf(floorf(y), 254.0f);
        float fx = x - bxf;
        float fy = y - byf;

        off[i] = (int)byf * WW + (int)bxf;
        w00[i] = (1.0f - fx) * (1.0f - fy);
        w01[i] = fx * (1.0f - fy);
        w10[i] = (1.0f - fx) * fy;
        w11[i] = fx * fy;
    }

    const float* ibase = input + (size_t)b * CC * HWSZ;
    float* obase = out + (size_t)b * CC * HWSZ + oy * WW + ox0;

    #pragma unroll 4
    for (int c = 0; c < CC; ++c) {
        const float* p = ibase + c * HWSZ;

        f2 a0, a1, b0, b1;   // pixel0: rows y0/y1 pairs; pixel1: same
        __builtin_memcpy(&a0, p + off[0], 8);
        __builtin_memcpy(&a1, p + off[0] + WW, 8);
        __builtin_memcpy(&b0, p + off[1], 8);
        __builtin_memcpy(&b1, p + off[1] + WW, 8);

        float o0 = a0.x * w00[0] + a0.y * w01[0] + a1.x * w10[0] + a1.y * w11[0];
        float o1 = b0.x * w00[1] + b0.y * w01[1] + b1.x * w10[1] + b1.y * w11[1];

        f2 ov; ov.x = o0; ov.y = o1;
        __builtin_nontemporal_store(ov, (f2*)(obase + c * HWSZ));
    }
}

extern "C" void kernel_launch(void* const* d_in, const int* in_sizes, int n_in,
                              void* d_out, int out_size, void* d_ws, size_t ws_size,
                              hipStream_t stream) {
    const float* input = (const float*)d_in[0];
    const float* theta = (const float*)d_in[1];
    float* out = (float*)d_out;

    dim3 block(256);
    dim3 grid(NBLK);   // 4096 blocks
    hipLaunchKernelGGL(st_bilinear_pair_kernel, grid, block, 0, stream,
                       input, theta, out);
}